// Round 9
// baseline (759.428 us; speedup 1.0000x reference)
//
#include <hip/hip_runtime.h>
#include <math.h>

// B=64, T=1000, S=96, A=32, INP=128, H=256. All I/O fp32.
// d_ws: pre fp16 [2][64000][256] = 65,536,000 B | h fp16 same = 65,536,000 B.
// W frag tables (393,216 B) live in the TAIL of the h region: ff reads them
// before rnn overwrites that region with h. Total ws use = 131,072,000 B.

typedef _Float16 half2_t __attribute__((ext_vector_type(2)));
typedef __attribute__((ext_vector_type(8))) short bf16x8;   // 8 bf16 in 4 VGPRs
typedef __attribute__((ext_vector_type(4))) float f32x4;

__device__ __forceinline__ float fdot2(half2_t a, half2_t b, float c) {
#if __has_builtin(__builtin_amdgcn_fdot2)
    return __builtin_amdgcn_fdot2(a, b, c, false);   // v_dot2_f32_f16
#else
    return c + (float)a[0] * (float)b[0] + (float)a[1] * (float)b[1];
#endif
}

__device__ __forceinline__ short f2bf(float f) {     // fp32 -> bf16 (RNE)
    unsigned u = __builtin_bit_cast(unsigned, f);
    return (short)((u + 0x7FFFu + ((u >> 16) & 1u)) >> 16);
}

// Barrier WITHOUT the vmcnt(0) drain __syncthreads() inserts. Safe when
// inter-wave communication is LDS-only (lgkmcnt covers DS ops).
__device__ __forceinline__ void barrier_lds() {
    __asm__ __volatile__("s_waitcnt lgkmcnt(0)" ::: "memory");
    __builtin_amdgcn_s_barrier();
}

// ---------------------------------------------------------------------------
// Kernel 0: pre-swizzle W into MFMA B-fragment tables (bf16).
// ---------------------------------------------------------------------------
__global__ __launch_bounds__(256, 1)
void prep_kernel(const float* __restrict__ fc11_w, const float* __restrict__ W_ih1,
                 const float* __restrict__ fc21_w, const float* __restrict__ W_ih2,
                 short* __restrict__ tab)
{
    const int e    = blockIdx.x * 256 + threadIdx.x;   // 96*256 = 24576 entries
    const int lane = e & 63;
    const int q = lane >> 4, m = lane & 15;
    const float* W;
    int k0, n;
    if (e < 8192) {                       // G1
        int t_ = e >> 6;
        int ks = t_ & 3, nt = (t_ >> 2) & 15, br = t_ >> 6;
        W = br ? fc21_w : fc11_w;
        k0 = ks * 32 + q * 8; n = nt * 16 + m;
    } else {                              // G2
        int t_ = (e - 8192) >> 6;
        int ks = t_ & 7, nt = (t_ >> 3) & 15, br = t_ >> 7;
        W = br ? W_ih2 : W_ih1;
        k0 = ks * 32 + q * 8; n = nt * 16 + m;
    }
    bf16x8 v;
#pragma unroll
    for (int j = 0; j < 8; ++j) v[j] = f2bf(W[(size_t)(k0 + j) * 256 + n]);
    ((bf16x8*)tab)[e] = v;
}

// ---------------------------------------------------------------------------
// Kernel 1: feed-forward via MFMA. 128-row blocks (grid 1000, 2 m-tiles per
// wave); b-frags loaded once per nt, reused across 2 m-tiles. (unchanged R8)
// ---------------------------------------------------------------------------
__global__ __launch_bounds__(256, 2)
void ff_kernel(const float* __restrict__ state,
               const float* __restrict__ action,
               const float* __restrict__ fc11_b, const float* __restrict__ fc21_b,
               const float* __restrict__ b_hh1, const float* __restrict__ b_ih1,
               const float* __restrict__ b_hh2, const float* __restrict__ b_ih2,
               const short* __restrict__ tab,
               _Float16* __restrict__ pre_out)
{
    __shared__ short X1[128 * 264];       // 67.6 KB bf16, +8 pad per row

    const int tile = blockIdx.x % 500;
    const int br   = blockIdx.x / 500;
    const int tid  = threadIdx.x;
    const int w    = tid >> 6;
    const int lane = tid & 63;
    const int q = lane >> 4, m = lane & 15;
    const int row0 = tile * 128;

    const float* ba = br ? fc21_b : fc11_b;
    const float* bh = br ? b_hh2 : b_hh1;
    const float* bi = br ? b_ih2 : b_ih1;
    const bf16x8* tG1 = (const bf16x8*)tab + (size_t)br * 4096;
    const bf16x8* tG2 = (const bf16x8*)tab + 8192 + (size_t)br * 8192;

    float ba_v[16], bb_v[16];
#pragma unroll
    for (int nt = 0; nt < 16; ++nt) {
        int c = nt * 16 + m;
        ba_v[nt] = ba[c];
        bb_v[nt] = bh[c] + bi[c];
    }

    bf16x8 af[2][4];
#pragma unroll
    for (int mt = 0; mt < 2; ++mt) {
        const int rw = row0 + 64 * mt + 16 * w + m;
#pragma unroll
        for (int ks = 0; ks < 4; ++ks) {
            int k0 = ks * 32 + q * 8;
            const float* src = (k0 < 96) ? (state  + (size_t)rw * 96 + k0)
                                         : (action + (size_t)rw * 32 + (k0 - 96));
            float4 x0 = *(const float4*)src;
            float4 x1 = *(const float4*)(src + 4);
            bf16x8 a;
            a[0] = f2bf(x0.x); a[1] = f2bf(x0.y); a[2] = f2bf(x0.z); a[3] = f2bf(x0.w);
            a[4] = f2bf(x1.x); a[5] = f2bf(x1.y); a[6] = f2bf(x1.z); a[7] = f2bf(x1.w);
            af[mt][ks] = a;
        }
    }

#pragma unroll 4
    for (int nt = 0; nt < 16; ++nt) {
        bf16x8 bf[4];
#pragma unroll
        for (int ks = 0; ks < 4; ++ks) bf[ks] = tG1[(nt * 4 + ks) * 64 + lane];
#pragma unroll
        for (int mt = 0; mt < 2; ++mt) {
            f32x4 acc = {0.f, 0.f, 0.f, 0.f};
#pragma unroll
            for (int ks = 0; ks < 4; ++ks)
                acc = __builtin_amdgcn_mfma_f32_16x16x32_bf16(af[mt][ks], bf[ks], acc, 0, 0, 0);
#pragma unroll
            for (int r = 0; r < 4; ++r) {     // D: col=lane&15, row=q*4+r
                float v = acc[r] + ba_v[nt];
                v = v > 0.f ? v : 0.f;
                X1[(64 * mt + 16 * w + q * 4 + r) * 264 + nt * 16 + m] = f2bf(v);
            }
        }
    }
    // X1 rows for wave w's m-tiles written+read by THIS wave only -> no barrier.

    bf16x8 a2[2][8];
#pragma unroll
    for (int mt = 0; mt < 2; ++mt)
#pragma unroll
        for (int ks = 0; ks < 8; ++ks)
            a2[mt][ks] = *(const bf16x8*)&X1[(64 * mt + 16 * w + m) * 264 + ks * 32 + q * 8];

    _Float16* pre = pre_out + (size_t)br * 64000u * 256u;
#pragma unroll 2
    for (int nt = 0; nt < 16; ++nt) {
        bf16x8 bg[8];
#pragma unroll
        for (int ks = 0; ks < 8; ++ks) bg[ks] = tG2[(nt * 8 + ks) * 64 + lane];
#pragma unroll
        for (int mt = 0; mt < 2; ++mt) {
            f32x4 acc = {0.f, 0.f, 0.f, 0.f};
#pragma unroll
            for (int ks = 0; ks < 8; ++ks)
                acc = __builtin_amdgcn_mfma_f32_16x16x32_bf16(a2[mt][ks], bg[ks], acc, 0, 0, 0);
#pragma unroll
            for (int r = 0; r < 4; ++r) {
                float v = acc[r] + bb_v[nt];
                pre[(size_t)(row0 + 64 * mt + 16 * w + q * 4 + r) * 256 + nt * 16 + m] = (_Float16)v;
            }
        }
    }
}

// ---------------------------------------------------------------------------
// Kernel 2: recurrence. CHANGE vs R8: the 128 weight half2's are 128 NAMED
// scalar variables whose values are produced by volatile v_mov_b32 inline
// asm. A volatile-asm def cannot be rematerialized or re-executed: with the
// 512-VGPR budget (waves_per_eu(1,1)) the allocator must keep them resident.
// This is the single-variable test of the weight-reload theory (R6-R8:
// VGPR_Count 88/92/132, dur stuck ~1450 cyc/step).
// ---------------------------------------------------------------------------
#define B2(x) __builtin_bit_cast(half2_t, x)

#define DECLW(i) unsigned w0_##i, w1_##i, w2_##i, w3_##i;

#define INITW(i) { \
    float4 lo = *(const float4*)(Whh + (size_t)(k0 + 2 * i) * 256 + c0); \
    float4 hi = *(const float4*)(Whh + (size_t)(k0 + 2 * i + 1) * 256 + c0); \
    unsigned a0 = __builtin_bit_cast(unsigned, half2_t{(_Float16)lo.x, (_Float16)hi.x}); \
    unsigned a1 = __builtin_bit_cast(unsigned, half2_t{(_Float16)lo.y, (_Float16)hi.y}); \
    unsigned a2 = __builtin_bit_cast(unsigned, half2_t{(_Float16)lo.z, (_Float16)hi.z}); \
    unsigned a3 = __builtin_bit_cast(unsigned, half2_t{(_Float16)lo.w, (_Float16)hi.w}); \
    __asm__ __volatile__("v_mov_b32 %0, %1" : "=v"(w0_##i) : "v"(a0)); \
    __asm__ __volatile__("v_mov_b32 %0, %1" : "=v"(w1_##i) : "v"(a1)); \
    __asm__ __volatile__("v_mov_b32 %0, %1" : "=v"(w2_##i) : "v"(a2)); \
    __asm__ __volatile__("v_mov_b32 %0, %1" : "=v"(w3_##i) : "v"(a3)); \
}

// one k-chunk of 8: hh[p] pairs with weight index i = 4k+p (k-pair 8k+2p,+1)
#define KSTEP(k, i0, i1, i2, i3) { \
    float4 v = hb[k]; \
    const half2_t* hh = (const half2_t*)&v; \
    sA0 = fdot2(hh[0], B2(w0_##i0), sA0); sA1 = fdot2(hh[0], B2(w1_##i0), sA1); \
    sA2 = fdot2(hh[0], B2(w2_##i0), sA2); sA3 = fdot2(hh[0], B2(w3_##i0), sA3); \
    sA0 = fdot2(hh[1], B2(w0_##i1), sA0); sA1 = fdot2(hh[1], B2(w1_##i1), sA1); \
    sA2 = fdot2(hh[1], B2(w2_##i1), sA2); sA3 = fdot2(hh[1], B2(w3_##i1), sA3); \
    sB0 = fdot2(hh[2], B2(w0_##i2), sB0); sB1 = fdot2(hh[2], B2(w1_##i2), sB1); \
    sB2 = fdot2(hh[2], B2(w2_##i2), sB2); sB3 = fdot2(hh[2], B2(w3_##i2), sB3); \
    sB0 = fdot2(hh[3], B2(w0_##i3), sB0); sB1 = fdot2(hh[3], B2(w1_##i3), sB1); \
    sB2 = fdot2(hh[3], B2(w2_##i3), sB2); sB3 = fdot2(hh[3], B2(w3_##i3), sB3); \
}

__global__ __launch_bounds__(256)
__attribute__((amdgpu_waves_per_eu(1, 1)))
void rnn_kernel(const _Float16* __restrict__ pre_all,
                const float* __restrict__ hn,
                const float* __restrict__ W_hh1,
                const float* __restrict__ W_hh2,
                _Float16* __restrict__ h_out)
{
    __shared__ _Float16 hbuf[256];
    __shared__ float part[2][4][256];   // [parity][wave][col] = 8 KB

    const int wg = blockIdx.x;          // 0..127
    const int br = wg >> 6;
    const int b  = wg & 63;
    const float* Whh = br ? W_hh2 : W_hh1;
    const _Float16* pre = pre_all + ((size_t)br * 64000u + (size_t)b * 1000u) * 256u;
    _Float16* hg = h_out + ((size_t)br * 64000u + (size_t)b * 1000u) * 256u;

    const int t  = threadIdx.x;
    const int w  = t >> 6;              // wave id = k-slice
    const int l  = t & 63;
    const int k0 = w * 64;
    const int c0 = l * 4;               // 4 columns per lane

    DECLW(0)  DECLW(1)  DECLW(2)  DECLW(3)  DECLW(4)  DECLW(5)  DECLW(6)  DECLW(7)
    DECLW(8)  DECLW(9)  DECLW(10) DECLW(11) DECLW(12) DECLW(13) DECLW(14) DECLW(15)
    DECLW(16) DECLW(17) DECLW(18) DECLW(19) DECLW(20) DECLW(21) DECLW(22) DECLW(23)
    DECLW(24) DECLW(25) DECLW(26) DECLW(27) DECLW(28) DECLW(29) DECLW(30) DECLW(31)

    INITW(0)  INITW(1)  INITW(2)  INITW(3)  INITW(4)  INITW(5)  INITW(6)  INITW(7)
    INITW(8)  INITW(9)  INITW(10) INITW(11) INITW(12) INITW(13) INITW(14) INITW(15)
    INITW(16) INITW(17) INITW(18) INITW(19) INITW(20) INITW(21) INITW(22) INITW(23)
    INITW(24) INITW(25) INITW(26) INITW(27) INITW(28) INITW(29) INITW(30) INITW(31)

    hbuf[t] = (_Float16)hn[b * 256 + t];
    barrier_lds();

    float pre_c = (float)pre[t];
    float pre_n = (float)pre[256 + t];

    for (int tt = 0; tt < 1000; ++tt) {
        // issue t+2 prefetch early; stays in flight across the barrier
        const int t2 = (tt + 2 < 1000) ? (tt + 2) : 999;
        const float pre_n2 = (float)pre[(size_t)t2 * 256 + t];

        const float4* hb = (const float4*)&hbuf[k0];
        float sA0 = 0.f, sA1 = 0.f, sA2 = 0.f, sA3 = 0.f;
        float sB0 = 0.f, sB1 = 0.f, sB2 = 0.f, sB3 = 0.f;

        KSTEP(0,  0,  1,  2,  3)
        KSTEP(1,  4,  5,  6,  7)
        KSTEP(2,  8,  9, 10, 11)
        KSTEP(3, 12, 13, 14, 15)
        KSTEP(4, 16, 17, 18, 19)
        KSTEP(5, 20, 21, 22, 23)
        KSTEP(6, 24, 25, 26, 27)
        KSTEP(7, 28, 29, 30, 31)

        const int pp = tt & 1;
        *(float4*)&part[pp][w][c0] =
            float4{sA0 + sB0, sA1 + sB1, sA2 + sB2, sA3 + sB3};
        barrier_lds();                              // publish partials

        // reduce col t (wave w owns its own next-step slice)
        const float z = ((part[pp][0][t] + part[pp][1][t]) +
                         (part[pp][2][t] + part[pp][3][t])) + pre_c;
        const float h = 1.0f / (1.0f + __expf(-z));
        const _Float16 h16 = (_Float16)h;
        hbuf[t] = h16;                              // same-wave consumer
        hg[(size_t)tt * 256 + t] = h16;             // in flight across barrier

        pre_c = pre_n;
        pre_n = pre_n2;
    }
}

// ---------------------------------------------------------------------------
// Kernel 3: q head. q[n] = h[n,:] . qw + qb. One thread per output.
// ---------------------------------------------------------------------------
__global__ __launch_bounds__(256, 2)
void q_kernel(const _Float16* __restrict__ h_all,
              const float* __restrict__ fc12_w, const float* __restrict__ fc12_b,
              const float* __restrict__ fc22_w, const float* __restrict__ fc22_b,
              float* __restrict__ out)
{
    const int n  = blockIdx.x * 256 + threadIdx.x;    // 500 blocks -> n < 128000
    const int br = (n >= 64000);                      // block-uniform
    const float* qwp = br ? fc22_w : fc12_w;
    const float  qb  = br ? fc22_b[0] : fc12_b[0];

    half2_t qw[128];
#pragma unroll
    for (int i = 0; i < 128; ++i)
        qw[i] = half2_t{(_Float16)qwp[2 * i], (_Float16)qwp[2 * i + 1]};

    const float4* hr = (const float4*)(h_all + (size_t)n * 256u);
    float s0 = qb, s1 = 0.f, s2 = 0.f, s3 = 0.f;
#pragma unroll
    for (int k = 0; k < 32; ++k) {
        float4 v = hr[k];
        const half2_t* hh = (const half2_t*)&v;
        s0 = fdot2(hh[0], qw[4 * k + 0], s0);
        s1 = fdot2(hh[1], qw[4 * k + 1], s1);
        s2 = fdot2(hh[2], qw[4 * k + 2], s2);
        s3 = fdot2(hh[3], qw[4 * k + 3], s3);
    }
    out[n] = (s0 + s1) + (s2 + s3);
}

// ---------------------------------------------------------------------------
extern "C" void kernel_launch(void* const* d_in, const int* in_sizes, int n_in,
                              void* d_out, int out_size, void* d_ws, size_t ws_size,
                              hipStream_t stream)
{
    const float* state  = (const float*)d_in[0];
    const float* action = (const float*)d_in[1];
    const float* hn     = (const float*)d_in[2];
    const float* fc11_w = (const float*)d_in[3];
    const float* fc11_b = (const float*)d_in[4];
    const float* W_hh1  = (const float*)d_in[5];
    const float* W_ih1  = (const float*)d_in[6];
    const float* b_hh1  = (const float*)d_in[7];
    const float* b_ih1  = (const float*)d_in[8];
    const float* fc12_w = (const float*)d_in[9];
    const float* fc12_b = (const float*)d_in[10];
    const float* fc21_w = (const float*)d_in[11];
    const float* fc21_b = (const float*)d_in[12];
    const float* W_hh2  = (const float*)d_in[13];
    const float* W_ih2  = (const float*)d_in[14];
    const float* b_hh2  = (const float*)d_in[15];
    const float* b_ih2  = (const float*)d_in[16];
    const float* fc22_w = (const float*)d_in[17];
    const float* fc22_b = (const float*)d_in[18];

    _Float16* pre = (_Float16*)d_ws;                         // 65,536,000 B
    _Float16* hbg = (_Float16*)d_ws + 32768000u;             // 65,536,000 B
    short* tab = (short*)((char*)d_ws + 130678784u);         // frag tables (tail of h region)

    prep_kernel<<<96, 256, 0, stream>>>(fc11_w, W_ih1, fc21_w, W_ih2, tab);
    ff_kernel<<<1000, 256, 0, stream>>>(state, action,
                                        fc11_b, fc21_b, b_hh1, b_ih1,
                                        b_hh2, b_ih2, tab, pre);
    rnn_kernel<<<128, 256, 0, stream>>>(pre, hn, W_hh1, W_hh2, hbg);
    q_kernel<<<500, 256, 0, stream>>>(hbg, fc12_w, fc12_b, fc22_w, fc22_b,
                                      (float*)d_out);
}